// Round 1
// baseline (801.331 us; speedup 1.0000x reference)
//
#include <hip/hip_runtime.h>
#include <math.h>

#define DD 64

// numpy pairwise_sum for n=64 (8-accumulator unrolled path), exact op order,
// no contraction/reassociation.
__device__ __forceinline__ float pairwise8_64(const float* s) {
    float r0 = s[0], r1 = s[1], r2 = s[2], r3 = s[3];
    float r4 = s[4], r5 = s[5], r6 = s[6], r7 = s[7];
#pragma unroll
    for (int i = 8; i < 64; i += 8) {
        r0 = __fadd_rn(r0, s[i + 0]);
        r1 = __fadd_rn(r1, s[i + 1]);
        r2 = __fadd_rn(r2, s[i + 2]);
        r3 = __fadd_rn(r3, s[i + 3]);
        r4 = __fadd_rn(r4, s[i + 4]);
        r5 = __fadd_rn(r5, s[i + 5]);
        r6 = __fadd_rn(r6, s[i + 6]);
        r7 = __fadd_rn(r7, s[i + 7]);
    }
    float a = __fadd_rn(r0, r1);
    float b = __fadd_rn(r2, r3);
    float c = __fadd_rn(r4, r5);
    float e = __fadd_rn(r6, r7);
    return __fadd_rn(__fadd_rn(a, b), __fadd_rn(c, e));
}

// ---------------- kernel 0: codebook row norms (np-bit-exact) ----------------
__global__ __launch_bounds__(256) void cnorm_kernel(const float* __restrict__ cb,
                                                    float* __restrict__ cnorm, int K) {
    int k = blockIdx.x * 256 + threadIdx.x;
    if (k >= K) return;
    const float* row = cb + (size_t)k * DD;
    float sq[DD];
#pragma unroll
    for (int d = 0; d < DD; ++d) sq[d] = __fmul_rn(row[d], row[d]);
    cnorm[k] = pairwise8_64(sq);
}

// ---------------- kernel 1: argmin over K codes per point --------------------
__global__ __launch_bounds__(256) void argmin_kernel(const float* __restrict__ z,
                                                     const float* __restrict__ cb,
                                                     const float* __restrict__ cnorm,
                                                     float* __restrict__ outIdxF,
                                                     int N, int K) {
    int n = blockIdx.x * 256 + threadIdx.x;
    if (n >= N) return;

    float zr[DD];
    const float4* zp = reinterpret_cast<const float4*>(z + (size_t)n * DD);
#pragma unroll
    for (int i = 0; i < DD / 4; ++i) {
        float4 v = zp[i];
        zr[4 * i + 0] = v.x;
        zr[4 * i + 1] = v.y;
        zr[4 * i + 2] = v.z;
        zr[4 * i + 3] = v.w;
    }

    // znorm: np-bit-exact (round each square, pairwise-8 sum)
    float sq[DD];
#pragma unroll
    for (int d = 0; d < DD; ++d) sq[d] = __fmul_rn(zr[d], zr[d]);
    float znorm = pairwise8_64(sq);

    float best = 3.402823466e+38f;
    int bidx = 0;

    for (int k = 0; k < K; k += 2) {
        const float* c0 = cb + (size_t)k * DD;
        float cn0 = cnorm[k];
        float cn1 = cnorm[k + 1];
        float d0 = 0.0f, d1 = 0.0f;
#pragma unroll
        for (int d = 0; d < DD; ++d) {
            d0 = __builtin_fmaf(zr[d], c0[d], d0);
            d1 = __builtin_fmaf(zr[d], c0[d + DD], d1);
        }
        // dist = fl( fl(znorm - 2*dot) + cnorm ); fma(-2,dot,znorm) has an
        // exact product so it rounds identically to (znorm - 2*dot).
        float t0 = __fadd_rn(__builtin_fmaf(-2.0f, d0, znorm), cn0);
        float t1 = __fadd_rn(__builtin_fmaf(-2.0f, d1, znorm), cn1);
        // strict < keeps the FIRST minimum (np.argmin tie-break), k order preserved
        if (t0 < best) { best = t0; bidx = k; }
        if (t1 < best) { best = t1; bidx = k + 1; }
    }
    outIdxF[n] = (float)bidx;
}

// ------------- kernel 2: gather z_q, write z_q_st, loss partials -------------
__global__ __launch_bounds__(256) void gather_kernel(const float* __restrict__ z,
                                                     const float* __restrict__ cb,
                                                     const float* __restrict__ idxF,
                                                     float* __restrict__ out0,
                                                     float* __restrict__ partials,
                                                     int N) {
    int gtid = blockIdx.x * 256 + threadIdx.x;
    int wave = gtid >> 6;
    int lane = threadIdx.x & 63;
    int nwaves = (gridDim.x * 256) >> 6;

    float acc = 0.0f;
    for (int n = wave; n < N; n += nwaves) {
        int idx = (int)idxF[n];
        float q = cb[(size_t)idx * DD + lane];
        float zv = z[(size_t)n * DD + lane];
        float t = q - zv;                       // stop_gradient(z_q - z), one round
        out0[(size_t)n * DD + lane] = zv + t;   // z + sg(z_q - z), second round
        acc += t * t;                           // (z_q - z)^2 accumulated (loss is loose-tolerance)
    }
    // wave reduce (64 lanes), deterministic
#pragma unroll
    for (int off = 32; off; off >>= 1) acc += __shfl_xor(acc, off);

    __shared__ float ws[4];
    if (lane == 0) ws[threadIdx.x >> 6] = acc;
    __syncthreads();
    if (threadIdx.x == 0) {
        float s = (ws[0] + ws[1]) + (ws[2] + ws[3]);
        partials[blockIdx.x] = s;
    }
}

// ---------------- kernel 3: finalize loss ------------------------------------
__global__ __launch_bounds__(256) void finalize_kernel(const float* __restrict__ partials,
                                                       int nPart, float* __restrict__ lossOut,
                                                       float totalElems) {
    __shared__ float sh[256];
    float s = 0.0f;
    for (int i = threadIdx.x; i < nPart; i += 256) s += partials[i];
    sh[threadIdx.x] = s;
    __syncthreads();
    for (int stride = 128; stride; stride >>= 1) {
        if (threadIdx.x < stride) sh[threadIdx.x] += sh[threadIdx.x + stride];
        __syncthreads();
    }
    if (threadIdx.x == 0) {
        float m = sh[0] / totalElems;            // totalElems = 2^23 -> exact division
        float p = 0.25f * m;                     // exact
        lossOut[0] = __fadd_rn(p, m);            // 0.25*mean + mean, np op order
    }
}

extern "C" void kernel_launch(void* const* d_in, const int* in_sizes, int n_in,
                              void* d_out, int out_size, void* d_ws, size_t ws_size,
                              hipStream_t stream) {
    const float* z = (const float*)d_in[0];
    const float* cb = (const float*)d_in[1];
    const int N = in_sizes[0] / DD;   // 131072
    const int K = in_sizes[1] / DD;   // 1024

    float* out0 = (float*)d_out;                       // z_q_st: N*DD floats
    float* lossOut = out0 + (size_t)N * DD;            // 1 float
    float* outIdxF = lossOut + 1;                      // N floats (indices as f32)

    float* cnorm = (float*)d_ws;                       // K floats
    float* partials = cnorm + K;                       // 2048 floats

    cnorm_kernel<<<(K + 255) / 256, 256, 0, stream>>>(cb, cnorm, K);
    argmin_kernel<<<(N + 255) / 256, 256, 0, stream>>>(z, cb, cnorm, outIdxF, N, K);

    const int nBlocks2 = 2048;
    gather_kernel<<<nBlocks2, 256, 0, stream>>>(z, cb, outIdxF, out0, partials, N);
    finalize_kernel<<<1, 256, 0, stream>>>(partials, nBlocks2, lossOut,
                                           (float)((size_t)N * DD));
}

// Round 2
// 336.047 us; speedup vs baseline: 2.3846x; 2.3846x over previous
//
#include <hip/hip_runtime.h>
#include <math.h>

#define DD 64
#define TK 256   // codebook tile: 256 codes x 64 dims x 4B = 64 KB LDS

typedef float f32x64 __attribute__((ext_vector_type(64)));

// ---------------- kernel 0: codebook row norms (np-bit-exact) ----------------
// numpy pairwise_sum for n=64: 8 accumulators stride-8, then pairwise combine.
__global__ __launch_bounds__(256) void cnorm_kernel(const float* __restrict__ cb,
                                                    float* __restrict__ cnorm, int K) {
    int k = blockIdx.x * 256 + threadIdx.x;
    if (k >= K) return;
    const float* row = cb + (size_t)k * DD;
    float r0 = __fmul_rn(row[0], row[0]);
    float r1 = __fmul_rn(row[1], row[1]);
    float r2 = __fmul_rn(row[2], row[2]);
    float r3 = __fmul_rn(row[3], row[3]);
    float r4 = __fmul_rn(row[4], row[4]);
    float r5 = __fmul_rn(row[5], row[5]);
    float r6 = __fmul_rn(row[6], row[6]);
    float r7 = __fmul_rn(row[7], row[7]);
#pragma unroll
    for (int i = 8; i < DD; i += 8) {
        r0 = __fadd_rn(r0, __fmul_rn(row[i + 0], row[i + 0]));
        r1 = __fadd_rn(r1, __fmul_rn(row[i + 1], row[i + 1]));
        r2 = __fadd_rn(r2, __fmul_rn(row[i + 2], row[i + 2]));
        r3 = __fadd_rn(r3, __fmul_rn(row[i + 3], row[i + 3]));
        r4 = __fadd_rn(r4, __fmul_rn(row[i + 4], row[i + 4]));
        r5 = __fadd_rn(r5, __fmul_rn(row[i + 5], row[i + 5]));
        r6 = __fadd_rn(r6, __fmul_rn(row[i + 6], row[i + 6]));
        r7 = __fadd_rn(r7, __fmul_rn(row[i + 7], row[i + 7]));
    }
    float a = __fadd_rn(r0, r1);
    float b = __fadd_rn(r2, r3);
    float c = __fadd_rn(r4, r5);
    float e = __fadd_rn(r6, r7);
    cnorm[k] = __fadd_rn(__fadd_rn(a, b), __fadd_rn(c, e));
}

// ---------------- kernel 1: argmin over K codes per point --------------------
// z point held in registers (ext_vector, constant-indexed); codebook staged in
// LDS tiles and read as wave-uniform broadcasts (conflict-free, ds_read_b128).
// Arithmetic is bit-identical to round 1 (verified absmax 0.0):
//   dot  = sequential FMA over d=0..63
//   dist = fl( fma(-2,dot,znorm) + cnorm )   [exact product => == znorm-2*dot]
//   argmin: strict < in k order (first-min tie-break, matches np.argmin)
__global__ __launch_bounds__(256, 2) void argmin_kernel(const float* __restrict__ z,
                                                        const float* __restrict__ cb,
                                                        const float* __restrict__ cnorm,
                                                        float* __restrict__ outIdxF,
                                                        int N, int K) {
    __shared__ float lds_cb[TK * DD];   // 64 KB
    __shared__ float lds_cn[TK];        // 1 KB

    const int n = blockIdx.x * 256 + threadIdx.x;
    const bool active = (n < N);

    // ---- load z point into registers ----
    f32x64 vz;
    {
        const float4* zp = reinterpret_cast<const float4*>(z + (size_t)(active ? n : 0) * DD);
#pragma unroll
        for (int i = 0; i < DD / 4; ++i) {
            float4 v = zp[i];
            vz[4 * i + 0] = v.x;
            vz[4 * i + 1] = v.y;
            vz[4 * i + 2] = v.z;
            vz[4 * i + 3] = v.w;
        }
    }

    // ---- znorm: np-bit-exact (round each square, pairwise-8 sum) ----
    float znorm;
    {
        float r0 = __fmul_rn(vz[0], vz[0]);
        float r1 = __fmul_rn(vz[1], vz[1]);
        float r2 = __fmul_rn(vz[2], vz[2]);
        float r3 = __fmul_rn(vz[3], vz[3]);
        float r4 = __fmul_rn(vz[4], vz[4]);
        float r5 = __fmul_rn(vz[5], vz[5]);
        float r6 = __fmul_rn(vz[6], vz[6]);
        float r7 = __fmul_rn(vz[7], vz[7]);
#pragma unroll
        for (int i = 8; i < DD; i += 8) {
            r0 = __fadd_rn(r0, __fmul_rn(vz[i + 0], vz[i + 0]));
            r1 = __fadd_rn(r1, __fmul_rn(vz[i + 1], vz[i + 1]));
            r2 = __fadd_rn(r2, __fmul_rn(vz[i + 2], vz[i + 2]));
            r3 = __fadd_rn(r3, __fmul_rn(vz[i + 3], vz[i + 3]));
            r4 = __fadd_rn(r4, __fmul_rn(vz[i + 4], vz[i + 4]));
            r5 = __fadd_rn(r5, __fmul_rn(vz[i + 5], vz[i + 5]));
            r6 = __fadd_rn(r6, __fmul_rn(vz[i + 6], vz[i + 6]));
            r7 = __fadd_rn(r7, __fmul_rn(vz[i + 7], vz[i + 7]));
        }
        float a = __fadd_rn(r0, r1);
        float b = __fadd_rn(r2, r3);
        float c = __fadd_rn(r4, r5);
        float e = __fadd_rn(r6, r7);
        znorm = __fadd_rn(__fadd_rn(a, b), __fadd_rn(c, e));
    }

    float best = 3.402823466e+38f;
    int bidx = 0;

    const int nTiles = K / TK;
    for (int t = 0; t < nTiles; ++t) {
        __syncthreads();   // previous tile fully consumed
        // cooperative stage: 16384 floats = 4096 float4, 16 per thread, coalesced
        {
            const float4* src = reinterpret_cast<const float4*>(cb + (size_t)t * TK * DD);
            float4* dst = reinterpret_cast<float4*>(lds_cb);
#pragma unroll
            for (int i = 0; i < (TK * DD / 4) / 256; ++i)
                dst[threadIdx.x + i * 256] = src[threadIdx.x + i * 256];
            if (threadIdx.x < TK)
                lds_cn[threadIdx.x] = cnorm[t * TK + threadIdx.x];
        }
        __syncthreads();

#pragma unroll 2
        for (int kk = 0; kk < TK; kk += 4) {
            const float* c = lds_cb + kk * DD;
            float a0 = 0.0f, a1 = 0.0f, a2 = 0.0f, a3 = 0.0f;
#pragma unroll
            for (int d = 0; d < DD; ++d) {
                a0 = __builtin_fmaf(vz[d], c[d], a0);
                a1 = __builtin_fmaf(vz[d], c[d + DD], a1);
                a2 = __builtin_fmaf(vz[d], c[d + 2 * DD], a2);
                a3 = __builtin_fmaf(vz[d], c[d + 3 * DD], a3);
            }
            float t0 = __fadd_rn(__builtin_fmaf(-2.0f, a0, znorm), lds_cn[kk + 0]);
            float t1 = __fadd_rn(__builtin_fmaf(-2.0f, a1, znorm), lds_cn[kk + 1]);
            float t2 = __fadd_rn(__builtin_fmaf(-2.0f, a2, znorm), lds_cn[kk + 2]);
            float t3 = __fadd_rn(__builtin_fmaf(-2.0f, a3, znorm), lds_cn[kk + 3]);
            int kb = t * TK + kk;
            if (t0 < best) { best = t0; bidx = kb + 0; }
            if (t1 < best) { best = t1; bidx = kb + 1; }
            if (t2 < best) { best = t2; bidx = kb + 2; }
            if (t3 < best) { best = t3; bidx = kb + 3; }
        }
    }
    if (active) outIdxF[n] = (float)bidx;
}

// ------------- kernel 2: gather z_q, write z_q_st, loss partials -------------
__global__ __launch_bounds__(256) void gather_kernel(const float* __restrict__ z,
                                                     const float* __restrict__ cb,
                                                     const float* __restrict__ idxF,
                                                     float* __restrict__ out0,
                                                     float* __restrict__ partials,
                                                     int N) {
    int gtid = blockIdx.x * 256 + threadIdx.x;
    int wave = gtid >> 6;
    int lane = threadIdx.x & 63;
    int nwaves = (gridDim.x * 256) >> 6;

    float acc = 0.0f;
    for (int n = wave; n < N; n += nwaves) {
        int idx = (int)idxF[n];
        float q = cb[(size_t)idx * DD + lane];
        float zv = z[(size_t)n * DD + lane];
        float t = q - zv;                       // stop_gradient(z_q - z), one round
        out0[(size_t)n * DD + lane] = zv + t;   // z + sg(z_q - z), second round
        acc += t * t;                           // loss accumulation (loose tolerance)
    }
#pragma unroll
    for (int off = 32; off; off >>= 1) acc += __shfl_xor(acc, off);

    __shared__ float ws[4];
    if (lane == 0) ws[threadIdx.x >> 6] = acc;
    __syncthreads();
    if (threadIdx.x == 0) {
        float s = (ws[0] + ws[1]) + (ws[2] + ws[3]);
        partials[blockIdx.x] = s;
    }
}

// ---------------- kernel 3: finalize loss ------------------------------------
__global__ __launch_bounds__(256) void finalize_kernel(const float* __restrict__ partials,
                                                       int nPart, float* __restrict__ lossOut,
                                                       float totalElems) {
    __shared__ float sh[256];
    float s = 0.0f;
    for (int i = threadIdx.x; i < nPart; i += 256) s += partials[i];
    sh[threadIdx.x] = s;
    __syncthreads();
    for (int stride = 128; stride; stride >>= 1) {
        if (threadIdx.x < stride) sh[threadIdx.x] += sh[threadIdx.x + stride];
        __syncthreads();
    }
    if (threadIdx.x == 0) {
        float m = sh[0] / totalElems;            // 2^23 divisor -> exact
        float p = 0.25f * m;                     // exact
        lossOut[0] = __fadd_rn(p, m);            // np op order
    }
}

extern "C" void kernel_launch(void* const* d_in, const int* in_sizes, int n_in,
                              void* d_out, int out_size, void* d_ws, size_t ws_size,
                              hipStream_t stream) {
    const float* z = (const float*)d_in[0];
    const float* cb = (const float*)d_in[1];
    const int N = in_sizes[0] / DD;   // 131072
    const int K = in_sizes[1] / DD;   // 1024

    float* out0 = (float*)d_out;                       // z_q_st: N*DD floats
    float* lossOut = out0 + (size_t)N * DD;            // 1 float
    float* outIdxF = lossOut + 1;                      // N floats (indices as f32)

    float* cnorm = (float*)d_ws;                       // K floats
    float* partials = cnorm + K;                       // 2048 floats

    cnorm_kernel<<<(K + 255) / 256, 256, 0, stream>>>(cb, cnorm, K);
    argmin_kernel<<<(N + 255) / 256, 256, 0, stream>>>(z, cb, cnorm, outIdxF, N, K);

    const int nBlocks2 = 2048;
    gather_kernel<<<nBlocks2, 256, 0, stream>>>(z, cb, outIdxF, out0, partials, N);
    finalize_kernel<<<1, 256, 0, stream>>>(partials, nBlocks2, lossOut,
                                           (float)((size_t)N * DD));
}